// Round 1
// baseline (899.425 us; speedup 1.0000x reference)
//
#include <hip/hip_runtime.h>

#define NN 30000
#define NE 120000
#define NG 256
#define FIN 16
#define FE 8
#define HD 32
#define TOUT 10
#define EPSV 1e-5f

__device__ __forceinline__ void atomAddF(float* p, float v) {
    unsafeAtomicAdd(p, v);  // global_atomic_add_f32, no CAS loop
}

// ---------------------------------------------------------------------------
// Edge kernel: one thread per edge. Computes
//   msg[e,o] = sum_{fb=0..8} coef_fb * sum_i xs[i] * Wrow_fb[i*HD+o]
// where fb<8 uses ea[e,fb] * nn_w rows, fb==8 uses 1.0 * nn_b (bias rows).
// Scatter-adds msg into agg[dst].
// xs staged in LDS transposed [i][lane]: bank = lane%32 -> 2 lanes/bank (free).
// W reads are wave-uniform -> scalar/broadcast loads.
// ---------------------------------------------------------------------------
template<int IN>
__global__ __launch_bounds__(64) void edge_kernel(
    const float* __restrict__ xin,   // [NN, IN]
    const float* __restrict__ ea,    // [NE, FE]
    const int*   __restrict__ eidx,  // [2, NE]
    const float* __restrict__ nn_w,  // [FE, IN*HD]
    const float* __restrict__ nn_b,  // [IN*HD]
    float*       __restrict__ agg)   // [NN, HD] (pre-zeroed)
{
    __shared__ float xs[IN][64];
    const int tid = threadIdx.x;
    const int e   = blockIdx.x * 64 + tid;
    const bool valid = (e < NE);
    const int eload = valid ? e : (NE - 1);

    const int s = eidx[eload];
    const int d = eidx[NE + eload];

    const float4* xr = (const float4*)(xin + s * IN);
    #pragma unroll
    for (int i = 0; i < IN / 4; ++i) {
        float4 v = xr[i];
        xs[4 * i + 0][tid] = v.x;
        xs[4 * i + 1][tid] = v.y;
        xs[4 * i + 2][tid] = v.z;
        xs[4 * i + 3][tid] = v.w;
    }

    const float4* er = (const float4*)(ea + (long)eload * FE);
    float4 ca = er[0], cb = er[1];
    const float eav[9] = {ca.x, ca.y, ca.z, ca.w, cb.x, cb.y, cb.z, cb.w, 1.0f};

    float acc[HD];
    #pragma unroll
    for (int o = 0; o < HD; ++o) acc[o] = 0.0f;

    #pragma unroll
    for (int fb = 0; fb < 9; ++fb) {
        const float a = eav[fb];
        const float* __restrict__ Wrow = (fb < 8) ? (nn_w + fb * (IN * HD)) : nn_b;
        #pragma unroll 4
        for (int i = 0; i < IN; ++i) {
            float z = a * xs[i][tid];
            const float* wp = Wrow + i * HD;
            #pragma unroll
            for (int o = 0; o < HD; ++o)
                acc[o] = fmaf(z, wp[o], acc[o]);
        }
    }

    if (!valid) return;
    float* ag = agg + (long)d * HD;
    #pragma unroll
    for (int o = 0; o < HD; ++o)
        atomAddF(ag + o, acc[o]);
}

// ---------------------------------------------------------------------------
// Degree (nodes per graph). batch is sorted -> per-wave run-length compress,
// one atomic per run instead of per node.
// ---------------------------------------------------------------------------
__global__ __launch_bounds__(256) void deg_kernel(
    const int* __restrict__ batch, float* __restrict__ deg)
{
    const int n    = blockIdx.x * 256 + threadIdx.x;
    const int lane = threadIdx.x & 63;
    const int g    = (n < NN) ? batch[n] : -1;
    const int prev = __shfl_up(g, 1);
    const bool head = (lane == 0) || (g != prev);
    const unsigned long long heads = __ballot(head);
    if (head && g >= 0) {
        unsigned long long higher = (lane < 63) ? (heads >> (lane + 1)) : 0ULL;
        int next = higher ? (lane + __ffsll(higher)) : 64;
        atomAddF(&deg[g], (float)(next - lane));
    }
}

// ---------------------------------------------------------------------------
// Node update for layers 1/2: h = relu(bn((agg + hin@root + bias) * deg^-0.5))
// thread per (node, out-channel)
// ---------------------------------------------------------------------------
template<int IN>
__global__ __launch_bounds__(256) void node_kernel(
    const float* __restrict__ hin,   // [NN, IN]
    const float* __restrict__ agg,   // [NN, HD]
    const float* __restrict__ root,  // [IN, HD]
    const float* __restrict__ bias,  // [HD]
    const int*   __restrict__ batch,
    const float* __restrict__ deg,   // [NG]
    const float* __restrict__ bn_g,
    const float* __restrict__ bn_b,
    const float* __restrict__ bn_m,
    const float* __restrict__ bn_v,
    float*       __restrict__ hout)  // [NN, HD]
{
    const int t = blockIdx.x * 256 + threadIdx.x;
    if (t >= NN * HD) return;
    const int n = t >> 5, o = t & 31;

    float v = agg[t] + bias[o];
    const float* hr = hin + (long)n * IN;
    #pragma unroll
    for (int i = 0; i < IN; ++i)
        v = fmaf(hr[i], root[i * HD + o], v);

    const int g = batch[n];
    float dg = deg[g];
    dg = dg > 0.0f ? dg : 1.0f;
    v *= 1.0f / sqrtf(dg);

    const float s = bn_g[o] / sqrtf(bn_v[o] + EPSV);
    v = (v - bn_m[o]) * s + bn_b[o];
    hout[t] = v > 0.0f ? v : 0.0f;
}

// ---------------------------------------------------------------------------
// Layer-3 node update fused with global mean-pool accumulation (sum part).
// Pair-reduce across the two nodes sharing a wave before the atomic.
// ---------------------------------------------------------------------------
__global__ __launch_bounds__(256) void node3_kernel(
    const float* __restrict__ hin,   // [NN, HD]
    const float* __restrict__ agg,   // [NN, HD]
    const float* __restrict__ root,  // [HD, HD]
    const float* __restrict__ bias,  // [HD]
    const int*   __restrict__ batch,
    float*       __restrict__ pooled) // [NG, HD] (pre-zeroed)
{
    const int t = blockIdx.x * 256 + threadIdx.x;
    if (t >= NN * HD) return;
    const int n = t >> 5, o = t & 31;

    float v = agg[t] + bias[o];
    const float* hr = hin + (long)n * HD;
    #pragma unroll
    for (int i = 0; i < HD; ++i)
        v = fmaf(hr[i], root[i * HD + o], v);

    const int g = batch[n];
    // lanes L and L^32 hold the same o for adjacent nodes; merge if same graph
    const int   g2 = __shfl(g, threadIdx.x ^ 32, 64);
    const float v2 = __shfl(v, threadIdx.x ^ 32, 64);
    if (g2 == g) {
        if (threadIdx.x & 32) return;   // partner lane retires
        v += v2;
    }
    atomAddF(&pooled[g * HD + o], v);
}

// ---------------------------------------------------------------------------
// Head: pooled/cnt -> relu(@w1+b1) @ w2 + b2. One thread per graph.
// ---------------------------------------------------------------------------
__global__ __launch_bounds__(64) void head_kernel(
    const float* __restrict__ pooled,
    const float* __restrict__ deg,
    const float* __restrict__ w1,  // [HD, HD]
    const float* __restrict__ b1,
    const float* __restrict__ w2,  // [HD, TOUT]
    const float* __restrict__ b2,
    float*       __restrict__ out) // [NG, TOUT]
{
    const int g = blockIdx.x * 64 + threadIdx.x;
    if (g >= NG) return;
    float cnt = deg[g];
    cnt = cnt > 1.0f ? cnt : 1.0f;

    float p[HD];
    #pragma unroll
    for (int i = 0; i < HD; ++i) p[i] = pooled[g * HD + i] / cnt;

    float hid[HD];
    #pragma unroll
    for (int j = 0; j < HD; ++j) {
        float a = b1[j];
        #pragma unroll
        for (int i = 0; i < HD; ++i)
            a = fmaf(p[i], w1[i * HD + j], a);
        hid[j] = a > 0.0f ? a : 0.0f;
    }
    #pragma unroll
    for (int t = 0; t < TOUT; ++t) {
        float a = b2[t];
        #pragma unroll
        for (int j = 0; j < HD; ++j)
            a = fmaf(hid[j], w2[j * TOUT + t], a);
        out[g * TOUT + t] = a;
    }
}

// ---------------------------------------------------------------------------
extern "C" void kernel_launch(void* const* d_in, const int* in_sizes, int n_in,
                              void* d_out, int out_size, void* d_ws, size_t ws_size,
                              hipStream_t stream)
{
    const float* x        = (const float*)d_in[0];
    const float* ea       = (const float*)d_in[1];
    const int*   eidx     = (const int*)  d_in[2];
    const int*   batch    = (const int*)  d_in[3];
    const float* c1_nn_w  = (const float*)d_in[4];
    const float* c1_nn_b  = (const float*)d_in[5];
    const float* c1_root  = (const float*)d_in[6];
    const float* c1_bias  = (const float*)d_in[7];
    const float* c2_nn_w  = (const float*)d_in[8];
    const float* c2_nn_b  = (const float*)d_in[9];
    const float* c2_root  = (const float*)d_in[10];
    const float* c2_bias  = (const float*)d_in[11];
    const float* c3_nn_w  = (const float*)d_in[12];
    const float* c3_nn_b  = (const float*)d_in[13];
    const float* c3_root  = (const float*)d_in[14];
    const float* c3_bias  = (const float*)d_in[15];
    const float* bn1_g    = (const float*)d_in[16];
    const float* bn1_b    = (const float*)d_in[17];
    const float* bn1_m    = (const float*)d_in[18];
    const float* bn1_v    = (const float*)d_in[19];
    const float* bn2_g    = (const float*)d_in[20];
    const float* bn2_b    = (const float*)d_in[21];
    const float* bn2_m    = (const float*)d_in[22];
    const float* bn2_v    = (const float*)d_in[23];
    const float* mlp_w1   = (const float*)d_in[24];
    const float* mlp_b1   = (const float*)d_in[25];
    const float* mlp_w2   = (const float*)d_in[26];
    const float* mlp_b2   = (const float*)d_in[27];
    float* out = (float*)d_out;

    float* agg    = (float*)d_ws;            // NN*HD
    float* h1     = agg + NN * HD;           // NN*HD
    float* h2     = h1  + NN * HD;           // NN*HD
    float* deg    = h2  + NN * HD;           // NG
    float* pooled = deg + NG;                // NG*HD

    const int edge_grid = (NE + 63) / 64;
    const int node_grid = (NN * HD + 255) / 256;

    hipMemsetAsync(agg,    0, sizeof(float) * NN * HD, stream);
    hipMemsetAsync(deg,    0, sizeof(float) * NG, stream);
    hipMemsetAsync(pooled, 0, sizeof(float) * NG * HD, stream);

    deg_kernel<<<(NN + 255) / 256, 256, 0, stream>>>(batch, deg);

    // ---- layer 1 ----
    edge_kernel<FIN><<<edge_grid, 64, 0, stream>>>(x, ea, eidx, c1_nn_w, c1_nn_b, agg);
    node_kernel<FIN><<<node_grid, 256, 0, stream>>>(x, agg, c1_root, c1_bias, batch, deg,
                                                    bn1_g, bn1_b, bn1_m, bn1_v, h1);
    // ---- layer 2 ----
    hipMemsetAsync(agg, 0, sizeof(float) * NN * HD, stream);
    edge_kernel<HD><<<edge_grid, 64, 0, stream>>>(h1, ea, eidx, c2_nn_w, c2_nn_b, agg);
    node_kernel<HD><<<node_grid, 256, 0, stream>>>(h1, agg, c2_root, c2_bias, batch, deg,
                                                   bn2_g, bn2_b, bn2_m, bn2_v, h2);
    // ---- layer 3 + pool ----
    hipMemsetAsync(agg, 0, sizeof(float) * NN * HD, stream);
    edge_kernel<HD><<<edge_grid, 64, 0, stream>>>(h2, ea, eidx, c3_nn_w, c3_nn_b, agg);
    node3_kernel<<<node_grid, 256, 0, stream>>>(h2, agg, c3_root, c3_bias, batch, pooled);

    // ---- head ----
    head_kernel<<<(NG + 63) / 64, 64, 0, stream>>>(pooled, deg, mlp_w1, mlp_b1,
                                                   mlp_w2, mlp_b2, out);
}

// Round 2
// 323.748 us; speedup vs baseline: 2.7782x; 2.7782x over previous
//
#include <hip/hip_runtime.h>

#define NN 30000
#define NE 120000
#define NG 256
#define FIN 16
#define HD 32
#define TOUT 10
#define EPSV 1e-5f

__device__ __forceinline__ void atomAddF(float* p, float v) {
    unsafeAtomicAdd(p, v);  // global_atomic_add_f32
}

// ---------------------------------------------------------------------------
// Graph sizes (nodes per graph). batch sorted -> run-length compress per wave.
// ---------------------------------------------------------------------------
__global__ __launch_bounds__(256) void deg_kernel(
    const int* __restrict__ batch, float* __restrict__ deg)
{
    const int n    = blockIdx.x * 256 + threadIdx.x;
    const int lane = threadIdx.x & 63;
    const int g    = (n < NN) ? batch[n] : -1;
    const int prev = __shfl_up(g, 1);
    const bool head = (lane == 0) || (g != prev);
    const unsigned long long heads = __ballot(head);
    if (head && g >= 0) {
        unsigned long long higher = (lane < 63) ? (heads >> (lane + 1)) : 0ULL;
        int next = higher ? (lane + __ffsll(higher)) : 64;
        atomAddF(&deg[g], (float)(next - lane));
    }
}

// ---------------------------------------------------------------------------
// CSR build: count in-degree, exclusive scan, scatter edge ids.
// ---------------------------------------------------------------------------
__global__ __launch_bounds__(256) void csr_count(
    const int* __restrict__ eidx, int* __restrict__ deg_in)
{
    const int e = blockIdx.x * 256 + threadIdx.x;
    if (e < NE) atomicAdd(&deg_in[eidx[NE + e]], 1);
}

__global__ __launch_bounds__(1024) void scan_kernel(
    const int* __restrict__ deg_in, int* __restrict__ row_start,
    int* __restrict__ cursor)
{
    __shared__ int wsum[16];
    __shared__ int carry_s;
    const int t = threadIdx.x;
    const int lane = t & 63;
    const int w = t >> 6;
    if (t == 0) carry_s = 0;
    __syncthreads();

    for (int base = 0; base < NN; base += 1024) {
        const int idx = base + t;
        const int v = (idx < NN) ? deg_in[idx] : 0;
        // inclusive scan within wave
        int s = v;
        #pragma unroll
        for (int off = 1; off < 64; off <<= 1) {
            int u = __shfl_up(s, off, 64);
            if (lane >= off) s += u;
        }
        if (lane == 63) wsum[w] = s;
        __syncthreads();
        if (w == 0) {
            int ws = (lane < 16) ? wsum[lane] : 0;
            #pragma unroll
            for (int off = 1; off < 16; off <<= 1) {
                int u = __shfl_up(ws, off, 64);
                if (lane >= off) ws += u;
            }
            if (lane < 16) wsum[lane] = ws;
        }
        __syncthreads();
        const int woff = (w > 0) ? wsum[w - 1] : 0;
        const int incl = s + woff;
        const int carry = carry_s;
        if (idx < NN) {
            const int excl = carry + incl - v;
            row_start[idx] = excl;
            cursor[idx]    = excl;
        }
        __syncthreads();                 // everyone has read carry_s
        if (t == 1023) carry_s += incl;  // incl at t=1023 == chunk total
        __syncthreads();
    }
    if (t == 0) row_start[NN] = carry_s;
}

__global__ __launch_bounds__(256) void csr_scatter(
    const int* __restrict__ eidx, int* __restrict__ cursor,
    int2* __restrict__ csr)
{
    const int e = blockIdx.x * 256 + threadIdx.x;
    if (e < NE) {
        const int d = eidx[NE + e];
        const int slot = atomicAdd(&cursor[d], 1);
        csr[slot] = make_int2(e, eidx[e]);  // (edge id, src id)
    }
}

// ---------------------------------------------------------------------------
// Fused per-node layer. 32 lanes per node (8 nodes / 256-block).
// Phase A (lane=i): T[f][i] = sum over incident edges of ea[e,f]*x[src,i],
//                   f=8 slot = sum x[src,i], f=9 slot = own row (for root).
// Phase B (lane=o): agg[o] = sum_{f,i} Wcat[f][i][o] * T[f][i] + bias,
//                   then gsn + BN + ReLU (or pool atomics for FINAL).
// No atomics for aggregation at all.
// ---------------------------------------------------------------------------
template<int IN, bool FINAL>
__global__ __launch_bounds__(256) void fused_layer(
    const float* __restrict__ hin,       // [NN, IN]
    const float* __restrict__ ea,        // [NE, 8]
    const int2*  __restrict__ csr,       // [NE] (e, s) grouped by dst
    const int*   __restrict__ row_start, // [NN+1]
    const float* __restrict__ nn_w,      // [8, IN*32]  ([f][i][o])
    const float* __restrict__ nn_b,      // [IN*32]     ([i][o])
    const float* __restrict__ root,      // [IN*32]     ([i][o])
    const float* __restrict__ bias,      // [32]
    const int*   __restrict__ batch,
    const float* __restrict__ deg_g,     // [NG]
    const float* __restrict__ bn_g,
    const float* __restrict__ bn_b,
    const float* __restrict__ bn_m,
    const float* __restrict__ bn_v,
    float*       __restrict__ out)       // [NN,32] or pooled [NG,32]
{
    __shared__ float Ts[8][10][IN];
    const int tid = threadIdx.x;
    const int ln  = tid >> 5;    // local node
    const int l   = tid & 31;
    const int d   = blockIdx.x * 8 + ln;   // NN%8==0: always valid
    const int i   = l & (IN - 1);

    float t[9];
    #pragma unroll
    for (int f = 0; f < 9; ++f) t[f] = 0.0f;

    const int p0 = row_start[d];
    const int p1 = row_start[d + 1];
    for (int p = p0; p < p1; ++p) {
        const int2 es = csr[p];
        const float xv = hin[(long)es.y * IN + i];
        const float4* er = (const float4*)(ea + (long)es.x * 8);
        const float4 a = er[0];
        const float4 b = er[1];
        t[0] = fmaf(a.x, xv, t[0]);
        t[1] = fmaf(a.y, xv, t[1]);
        t[2] = fmaf(a.z, xv, t[2]);
        t[3] = fmaf(a.w, xv, t[3]);
        t[4] = fmaf(b.x, xv, t[4]);
        t[5] = fmaf(b.y, xv, t[5]);
        t[6] = fmaf(b.z, xv, t[6]);
        t[7] = fmaf(b.w, xv, t[7]);
        t[8] += xv;
    }
    if (IN == 32 || l < IN) {
        #pragma unroll
        for (int f = 0; f < 9; ++f) Ts[ln][f][i] = t[f];
        Ts[ln][9][i] = hin[(long)d * IN + i];   // own row for root term
    }
    __syncthreads();

    float acc = bias[l];
    #pragma unroll
    for (int f = 0; f < 8; ++f) {
        const float* wp = nn_w + f * (IN * 32);
        const float4* Tv = (const float4*)(&Ts[ln][f][0]);
        #pragma unroll
        for (int i4 = 0; i4 < IN / 4; ++i4) {
            const float4 tv = Tv[i4];
            const float* w4 = wp + i4 * 128 + l;
            acc = fmaf(tv.x, w4[0],  acc);
            acc = fmaf(tv.y, w4[32], acc);
            acc = fmaf(tv.z, w4[64], acc);
            acc = fmaf(tv.w, w4[96], acc);
        }
    }
    {   // nn_b term
        const float4* Tv = (const float4*)(&Ts[ln][8][0]);
        #pragma unroll
        for (int i4 = 0; i4 < IN / 4; ++i4) {
            const float4 tv = Tv[i4];
            const float* w4 = nn_b + i4 * 128 + l;
            acc = fmaf(tv.x, w4[0],  acc);
            acc = fmaf(tv.y, w4[32], acc);
            acc = fmaf(tv.z, w4[64], acc);
            acc = fmaf(tv.w, w4[96], acc);
        }
    }
    {   // root term
        const float4* Tv = (const float4*)(&Ts[ln][9][0]);
        #pragma unroll
        for (int i4 = 0; i4 < IN / 4; ++i4) {
            const float4 tv = Tv[i4];
            const float* w4 = root + i4 * 128 + l;
            acc = fmaf(tv.x, w4[0],  acc);
            acc = fmaf(tv.y, w4[32], acc);
            acc = fmaf(tv.z, w4[64], acc);
            acc = fmaf(tv.w, w4[96], acc);
        }
    }

    const int g = batch[d];
    if (!FINAL) {
        float dg = deg_g[g];
        dg = dg > 0.0f ? dg : 1.0f;
        float v = acc * (1.0f / sqrtf(dg));
        const float s = bn_g[l] / sqrtf(bn_v[l] + EPSV);
        v = (v - bn_m[l]) * s + bn_b[l];
        out[(long)d * 32 + l] = v > 0.0f ? v : 0.0f;
    } else {
        float v = acc;
        // merge the two nodes sharing this wave if same graph (batch sorted)
        const int   g2 = __shfl(g, tid ^ 32, 64);
        const float v2 = __shfl(v, tid ^ 32, 64);
        if (g2 == g) {
            if (tid & 32) return;
            v += v2;
        }
        atomAddF(&out[g * 32 + l], v);
    }
}

// ---------------------------------------------------------------------------
// Head: pooled/cnt -> relu(@w1+b1) @ w2 + b2. One thread per graph.
// ---------------------------------------------------------------------------
__global__ __launch_bounds__(64) void head_kernel(
    const float* __restrict__ pooled,
    const float* __restrict__ deg,
    const float* __restrict__ w1,
    const float* __restrict__ b1,
    const float* __restrict__ w2,
    const float* __restrict__ b2,
    float*       __restrict__ out)
{
    const int g = blockIdx.x * 64 + threadIdx.x;
    if (g >= NG) return;
    float cnt = deg[g];
    cnt = cnt > 1.0f ? cnt : 1.0f;

    float p[HD];
    #pragma unroll
    for (int i = 0; i < HD; ++i) p[i] = pooled[g * HD + i] / cnt;

    float hid[HD];
    #pragma unroll
    for (int j = 0; j < HD; ++j) {
        float a = b1[j];
        #pragma unroll
        for (int i = 0; i < HD; ++i)
            a = fmaf(p[i], w1[i * HD + j], a);
        hid[j] = a > 0.0f ? a : 0.0f;
    }
    #pragma unroll
    for (int t = 0; t < TOUT; ++t) {
        float a = b2[t];
        #pragma unroll
        for (int j = 0; j < HD; ++j)
            a = fmaf(hid[j], w2[j * TOUT + t], a);
        out[g * TOUT + t] = a;
    }
}

// ---------------------------------------------------------------------------
extern "C" void kernel_launch(void* const* d_in, const int* in_sizes, int n_in,
                              void* d_out, int out_size, void* d_ws, size_t ws_size,
                              hipStream_t stream)
{
    const float* x        = (const float*)d_in[0];
    const float* ea       = (const float*)d_in[1];
    const int*   eidx     = (const int*)  d_in[2];
    const int*   batch    = (const int*)  d_in[3];
    const float* c1_nn_w  = (const float*)d_in[4];
    const float* c1_nn_b  = (const float*)d_in[5];
    const float* c1_root  = (const float*)d_in[6];
    const float* c1_bias  = (const float*)d_in[7];
    const float* c2_nn_w  = (const float*)d_in[8];
    const float* c2_nn_b  = (const float*)d_in[9];
    const float* c2_root  = (const float*)d_in[10];
    const float* c2_bias  = (const float*)d_in[11];
    const float* c3_nn_w  = (const float*)d_in[12];
    const float* c3_nn_b  = (const float*)d_in[13];
    const float* c3_root  = (const float*)d_in[14];
    const float* c3_bias  = (const float*)d_in[15];
    const float* bn1_g    = (const float*)d_in[16];
    const float* bn1_b    = (const float*)d_in[17];
    const float* bn1_m    = (const float*)d_in[18];
    const float* bn1_v    = (const float*)d_in[19];
    const float* bn2_g    = (const float*)d_in[20];
    const float* bn2_b    = (const float*)d_in[21];
    const float* bn2_m    = (const float*)d_in[22];
    const float* bn2_v    = (const float*)d_in[23];
    const float* mlp_w1   = (const float*)d_in[24];
    const float* mlp_b1   = (const float*)d_in[25];
    const float* mlp_w2   = (const float*)d_in[26];
    const float* mlp_b2   = (const float*)d_in[27];
    float* out = (float*)d_out;

    // workspace layout
    float* h1     = (float*)d_ws;            // NN*32
    float* h2     = h1 + NN * HD;            // NN*32
    float* deg_g  = h2 + NN * HD;            // NG
    float* pooled = deg_g + NG;              // NG*32
    int*   ibase  = (int*)(pooled + NG * HD);
    int2*  csr    = (int2*)ibase;            // NE int2 (8B-aligned offset)
    int*   deg_in = ibase + 2 * NE;          // NN
    int*   row_s  = deg_in + NN;             // NN+1
    int*   cursor = row_s + NN + 1;          // NN

    hipMemsetAsync(deg_in, 0, sizeof(int) * NN, stream);
    hipMemsetAsync(deg_g,  0, sizeof(float) * NG, stream);
    hipMemsetAsync(pooled, 0, sizeof(float) * NG * HD, stream);

    const int egrid = (NE + 255) / 256;
    const int ngrid = (NN + 255) / 256;

    deg_kernel <<<ngrid, 256, 0, stream>>>(batch, deg_g);
    csr_count  <<<egrid, 256, 0, stream>>>(eidx, deg_in);
    scan_kernel<<<1, 1024, 0, stream>>>(deg_in, row_s, cursor);
    csr_scatter<<<egrid, 256, 0, stream>>>(eidx, cursor, csr);

    const int lgrid = NN / 8;  // 3750, exact

    fused_layer<FIN, false><<<lgrid, 256, 0, stream>>>(
        x, ea, csr, row_s, c1_nn_w, c1_nn_b, c1_root, c1_bias,
        batch, deg_g, bn1_g, bn1_b, bn1_m, bn1_v, h1);

    fused_layer<HD, false><<<lgrid, 256, 0, stream>>>(
        h1, ea, csr, row_s, c2_nn_w, c2_nn_b, c2_root, c2_bias,
        batch, deg_g, bn2_g, bn2_b, bn2_m, bn2_v, h2);

    fused_layer<HD, true><<<lgrid, 256, 0, stream>>>(
        h2, ea, csr, row_s, c3_nn_w, c3_nn_b, c3_root, c3_bias,
        batch, deg_g, nullptr, nullptr, nullptr, nullptr, pooled);

    head_kernel<<<(NG + 63) / 64, 64, 0, stream>>>(pooled, deg_g, mlp_w1, mlp_b1,
                                                   mlp_w2, mlp_b2, out);
}